// Round 18
// baseline (127.941 us; speedup 1.0000x reference)
//
#include <hip/hip_runtime.h>
#include <hip/hip_bf16.h>
#include <math.h>

#define BB 16384
#define DD 768
#define NG 512                 // grid nodes per sign
#define GR 1024                // grid node rows (2 signs)
#define MROWS 1280             // 1024 nodes + 84 tables + pad (5*256)
#define CPS 511                // cells per sign
#define NCELL 1022             // total cells
#define MIXR 2048              // mixed rows (2044 used, pad to 8*256)

typedef __attribute__((ext_vector_type(8))) short bf16x8;
typedef __attribute__((ext_vector_type(4))) float f32x4;

// Static device scratch — referenced ONLY from device code.
__device__ short g_Abf[(size_t)MROWS * DD];         // bf16 feats: 0..1023 nodes, 1024..1107 tables, pad 0
__device__ short g_W[(size_t)2304 * DD];            // bf16 in_proj_w
__device__ short g_WoutBf[(size_t)DD * DD];         // bf16 out_proj_w
__device__ short g_qkv[(size_t)MROWS * 2304];       // bf16 q|k|v per row (no bias)
__device__ short g_QKp[(size_t)16 * MROWS * 128];   // z<8: q+bq per head (K-pad 128); z>=8: k+bk
__device__ short g_TabP[(size_t)16 * 128 * 128];    // z<8: k_tab+bk; z>=8: q_tab+bq
__device__ float g_scoref[(size_t)16 * MROWS * 128];// z<8: u-scores; z>=8: w-scores (f32)
__device__ float g_tnode[GR];                       // node t values (snapped)
__device__ int   g_creg[NCELL];                     // packed region per cell (midpoint)
__device__ short g_mixedS[(size_t)MIXR * DD];       // bf16 mixed rows per (cell,endpoint)
__device__ short g_preS[(size_t)MIXR * DD];         // bf16 PRE rows (no out bias)
__device__ float g_maxabs;

__device__ inline unsigned short f2bf(float x) {
    union { float f; unsigned u; } v; v.f = x;
    unsigned r = v.u + 0x7fffu + ((v.u >> 16) & 1u);
    return (unsigned short)(r >> 16);
}
__device__ inline float bf2f(unsigned short h) {
    union { unsigned u; float f; } v; v.u = ((unsigned)h) << 16;
    return v.f;
}

__device__ inline float gelu_exact(float x) {
    return 0.5f * x * (1.0f + erff(x * 0.70710678118654752440f));
}

__device__ inline float block_sum256(float v, float* sbuf) {
    #pragma unroll
    for (int o = 32; o; o >>= 1) v += __shfl_xor(v, o);
    __syncthreads();
    if ((threadIdx.x & 63) == 0) sbuf[threadIdx.x >> 6] = v;
    __syncthreads();
    return sbuf[0] + sbuf[1] + sbuf[2] + sbuf[3];
}

// region of a scalar x (exact reference math)
__device__ inline int region_of(float x, const float* __restrict__ boundaries,
                                int* bin_o, int* sfi_o, int* si_o) {
    int bin = 0;
    #pragma unroll
    for (int j = 0; j < 20; ++j) bin += (boundaries[j] < x) ? 1 : 0;
    bin = min(bin, 19);
    float sf = floorf(log10f(fabsf(x) + 1e-10f));
    int sfi = min(max((int)sf + 10, 0), 15);
    int si = (x > 0.f) ? 2 : ((x < 0.f) ? 0 : 1);
    *bin_o = bin; *sfi_o = sfi; *si_o = si;
    return (bin << 6) | (sfi << 2) | si;
}

// single block, 1024 threads: max|x| -> g_maxabs
__global__ __launch_bounds__(1024) void k_absmax(const float* __restrict__ number) {
    const float4* n4 = reinterpret_cast<const float4*>(number);
    float v = 0.f;
    #pragma unroll
    for (int i = 0; i < 4; ++i) {
        float4 x = n4[threadIdx.x + 1024 * i];
        v = fmaxf(fmaxf(fabsf(x.x), fabsf(x.y)), fmaxf(fmaxf(fabsf(x.z), fabsf(x.w)), v));
    }
    #pragma unroll
    for (int o = 32; o; o >>= 1) v = fmaxf(v, __shfl_xor(v, o));
    __shared__ float sb[16];
    if ((threadIdx.x & 63) == 0) sb[threadIdx.x >> 6] = v;
    __syncthreads();
    if (threadIdx.x == 0) {
        float m = sb[0];
        #pragma unroll
        for (int i = 1; i < 16; ++i) m = fmaxf(m, sb[i]);
        g_maxabs = m;
    }
}

// Block roles (fgrid long-pole first — R17 layout + R16 zero-pad tails):
// 0-255 fgrid node rows, 256-831 weight cast (4 float4/thread), 832-851 mag rows,
// 852-867 scale rows, 868-915 ctx rows, 916-1087 Abf pad zero,
// 1088-1407 QKp K-pad zero (cols 96..127), 1408-1535 TabP zero.
__global__ void k_tables(const float* __restrict__ mag_emb,
                         const float* __restrict__ se_w1, const float* __restrict__ se_b1,
                         const float* __restrict__ se_g1, const float* __restrict__ se_bt1,
                         const float* __restrict__ se_w2, const float* __restrict__ se_b2,
                         const float* __restrict__ ce_w, const float* __restrict__ ce_b,
                         const float* __restrict__ ce_g, const float* __restrict__ ce_bt,
                         const float* __restrict__ in_proj_w, const float* __restrict__ out_proj_w,
                         const float* __restrict__ ne_w, const float* __restrict__ ne_b,
                         const float* __restrict__ ne_g, const float* __restrict__ ne_bt) {
    __shared__ float sbuf[4];
    __shared__ float sh[192];
    const int t = threadIdx.x;
    const int blk = blockIdx.x;
    if (blk < 256) {
        // fgrid node rows: one wave per node r in [0,1024). Snap interior nodes
        // to region breakpoints so cells are region-uniform.
        const int wid = t >> 6, lane = t & 63;
        const int r = blk * 4 + wid;
        const float mx = g_maxabs;
        const float L = log1pf(mx);
        const float dt = L / (float)(NG - 1);
        const int ri = r & (NG - 1);
        float tt = (float)ri * dt;
        if (ri > 0 && ri < NG - 1) {
            #pragma unroll
            for (int k = 0; k < 16; ++k) {
                float tb = log1pf(__expf((float)k * 2.302585093f));
                if (tb < L && (int)(tb / dt + 0.5f) == ri) tt = tb;
            }
            #pragma unroll
            for (int j = 0; j < 9; ++j) {
                float tb = log1pf(__expf((float)j * 1.875f * 2.302585093f));
                if (tb < L && (int)(tb / dt + 0.5f) == ri) tt = tb;
            }
        }
        if (lane == 0) g_tnode[r] = tt;
        const float ax = expm1f(tt);
        const float sgn = (r >= NG) ? -1.f : 1.f;
        const float a = sgn * ax / (mx + 1e-10f);
        const float b = tt / (L + 1e-10f);
        float pre[12];
        float s = 0.f;
        #pragma unroll
        for (int j = 0; j < 12; ++j) {
            int d = lane + 64 * j;
            float2 w = *reinterpret_cast<const float2*>(&ne_w[2 * d]);
            pre[j] = a * w.x + b * w.y + ne_b[d];
            s += pre[j];
        }
        #pragma unroll
        for (int o = 32; o; o >>= 1) s += __shfl_xor(s, o);
        float m = s / 768.f;
        float q = 0.f;
        #pragma unroll
        for (int j = 0; j < 12; ++j) { float dd = pre[j] - m; q += dd * dd; }
        #pragma unroll
        for (int o = 32; o; o >>= 1) q += __shfl_xor(q, o);
        float inv = 1.f / sqrtf(q / 768.f + 1e-5f);
        #pragma unroll
        for (int j = 0; j < 12; ++j) {
            int d = lane + 64 * j;
            g_Abf[(size_t)r * DD + d] = (short)f2bf(gelu_exact((pre[j] - m) * inv * ne_g[d] + ne_bt[d]));
        }
    } else if (blk < 832) {
        // weight cast: 4 float4 per thread, 1024 float4 per block (576 blocks).
        #pragma unroll
        for (int ii = 0; ii < 4; ++ii) {
            int i = (blk - 256) * 1024 + t + 256 * ii;
            const bool second = (i >= 442368);
            const float* src = second ? out_proj_w : in_proj_w;
            short* dst = second ? g_WoutBf : g_W;
            int j = second ? (i - 442368) : i;
            const float4 v = *reinterpret_cast<const float4*>(&src[(size_t)j * 4]);
            ushort4 o;
            o.x = f2bf(v.x); o.y = f2bf(v.y); o.z = f2bf(v.z); o.w = f2bf(v.w);
            *reinterpret_cast<ushort4*>(&dst[(size_t)j * 4]) = o;
        }
    } else if (blk < 852) {
        int mrow = blk - 832;
        #pragma unroll
        for (int i = 0; i < 3; ++i) {
            int d = t + 256 * i;
            g_Abf[(size_t)(GR + mrow) * DD + d] = (short)f2bf(mag_emb[mrow * DD + d]);
        }
    } else if (blk < 868) {
        int sfi = blk - 852;
        float sf = (float)(sfi - 10);
        float pre = 0.f;
        if (t < 192) pre = sf * se_w1[t] + se_b1[t];
        float s = block_sum256(t < 192 ? pre : 0.f, sbuf);
        float m = s / 192.f;
        float dd = (t < 192) ? (pre - m) : 0.f;
        float vv = block_sum256(dd * dd, sbuf);
        float inv = 1.f / sqrtf(vv / 192.f + 1e-5f);
        if (t < 192) sh[t] = gelu_exact((pre - m) * inv * se_g1[t] + se_bt1[t]);
        __syncthreads();
        #pragma unroll
        for (int i = 0; i < 3; ++i) {
            int d = t + 256 * i;
            float acc = se_b2[d];
            for (int j = 0; j < 192; ++j) acc += se_w2[d * 192 + j] * sh[j];
            g_Abf[(size_t)(GR + 20 + sfi) * DD + d] = (short)f2bf(acc);
        }
    } else if (blk < 916) {
        int c = blk - 868;
        int si = c >> 4, sfi = c & 15;
        float f0 = (float)(si - 1);
        float f1 = (float)(sfi - 10) / 16.f;
        float pre[3];
        float ps = 0.f;
        #pragma unroll
        for (int i = 0; i < 3; ++i) {
            int d = t + 256 * i;
            pre[i] = f0 * ce_w[2 * d] + f1 * ce_w[2 * d + 1] + ce_b[d];
            ps += pre[i];
        }
        float s = block_sum256(ps, sbuf);
        float m = s / 768.f;
        float qs = 0.f;
        #pragma unroll
        for (int i = 0; i < 3; ++i) { float dd = pre[i] - m; qs += dd * dd; }
        float vv = block_sum256(qs, sbuf);
        float inv = 1.f / sqrtf(vv / 768.f + 1e-5f);
        #pragma unroll
        for (int i = 0; i < 3; ++i) {
            int d = t + 256 * i;
            g_Abf[(size_t)(GR + 36 + c) * DD + d] =
                (short)f2bf(gelu_exact((pre[i] - m) * inv * ce_g[d] + ce_bt[d]));
        }
    } else if (blk < 1088) {
        int row = GR + 84 + (blk - 916);   // 1108 .. 1279
        #pragma unroll
        for (int i = 0; i < 3; ++i) g_Abf[(size_t)row * DD + t + 256 * i] = 0;
    } else if (blk < 1408) {
        // zero QKp K-pad cols 96..127: 16 z * 1280 rows * 4 chunks of 8 shorts
        const int i = (blk - 1088) * 256 + t;          // < 81920
        const int z = i / (MROWS * 4);
        const int rem = i % (MROWS * 4);
        const int row = rem >> 2, c = rem & 3;
        const bf16x8 zv = {0, 0, 0, 0, 0, 0, 0, 0};
        *reinterpret_cast<bf16x8*>(g_QKp + ((size_t)z * MROWS + row) * 128 + 96 + c * 8) = zv;
    } else {
        // zero all of TabP (gemm0 scatter fills j<84, d<96 afterwards)
        const int i = (blk - 1408) * 256 + t;          // < 32768
        const bf16x8 zv = {0, 0, 0, 0, 0, 0, 0, 0};
        *reinterpret_cast<bf16x8*>(g_TabP + (size_t)i * 8) = zv;
    }
}

// C[m][n] = sum_k A[m][k]*B[n][k] (bf16 in, fp32 MFMA accum). R10 config.
// which==0: g_Abf(1280) @ g_W -> g_qkv (N=2304); epilogue ALSO scatters q/k
//           (+fp32 bias, single rounding) into g_QKp (all rows) and g_TabP
//           (table rows). (R16-proven.)
// which==1: g_mixedS(2048) @ g_WoutBf -> g_preS (N=768)
// which==2: per-head score GEMMs, grid.z=16: g_QKp[z] @ g_TabP[z] -> g_scoref[z] F32
__global__ __launch_bounds__(512, 4) void gemm_bt(int which, int N, int K,
                                                  const float* __restrict__ bias) {
    const int z = blockIdx.z;
    const short* A = (which == 0) ? g_Abf : (which == 1) ? g_mixedS : g_QKp + (size_t)z * MROWS * 128;
    const short* B = (which == 0) ? g_W : (which == 2) ? g_TabP + (size_t)z * 128 * 128 : g_WoutBf;
    short* C = (which == 0) ? g_qkv : g_preS;
    float* Cf = g_scoref + (size_t)z * MROWS * 128;

    __shared__ short As[256 * 64];
    __shared__ short Bs[128 * 64];
    const int t = threadIdx.x;

    const int GX = gridDim.x;
    const int nwg = GX * gridDim.y;
    const int lin = blockIdx.y * GX + blockIdx.x;
    const int qq = nwg >> 3, rr = nwg & 7;
    const int xcd = lin & 7, idx = lin >> 3;
    const int nl = (xcd < rr ? xcd * (qq + 1) : rr * (qq + 1) + (xcd - rr) * qq) + idx;
    const int m0 = (nl / GX) * 256, n0 = (nl % GX) * 128;

    const int wid = t >> 6, lane = t & 63;
    const int wm = wid >> 1, wn = wid & 1;
    const int fr = lane & 15, ks = lane >> 4;

    f32x4 acc[4][4];
    #pragma unroll
    for (int m = 0; m < 4; ++m)
        #pragma unroll
        for (int n = 0; n < 4; ++n) acc[m][n] = (f32x4){0.f, 0.f, 0.f, 0.f};

    for (int k0 = 0; k0 < K; k0 += 64) {
        #pragma unroll
        for (int i = 0; i < 4; ++i) {
            int L = t + 512 * i;
            int row = L >> 3, sp = L & 7;
            int s = sp ^ (row & 7);
            const short* srcA = A + (size_t)(m0 + row) * K + k0 + s * 8;
            __builtin_amdgcn_global_load_lds(
                (const __attribute__((address_space(1))) unsigned int*)srcA,
                (__attribute__((address_space(3))) unsigned int*)((char*)As + L * 16), 16, 0, 0);
        }
        #pragma unroll
        for (int i = 0; i < 2; ++i) {
            int L = t + 512 * i;
            int row = L >> 3, sp = L & 7;
            int s = sp ^ (row & 7);
            const short* srcB = B + (size_t)(n0 + row) * K + k0 + s * 8;
            __builtin_amdgcn_global_load_lds(
                (const __attribute__((address_space(1))) unsigned int*)srcB,
                (__attribute__((address_space(3))) unsigned int*)((char*)Bs + L * 16), 16, 0, 0);
        }
        __syncthreads();
        #pragma unroll
        for (int kk = 0; kk < 2; ++kk) {
            bf16x8 af[4], bfr[4];
            #pragma unroll
            for (int m = 0; m < 4; ++m) {
                int row = wm * 64 + m * 16 + fr;
                int off = row * 128 + ((((kk << 2) | ks) ^ (row & 7)) * 16);
                af[m] = *(const bf16x8*)((const char*)As + off);
            }
            #pragma unroll
            for (int n = 0; n < 4; ++n) {
                int row = wn * 64 + n * 16 + fr;
                int off = row * 128 + ((((kk << 2) | ks) ^ (row & 7)) * 16);
                bfr[n] = *(const bf16x8*)((const char*)Bs + off);
            }
            #pragma unroll
            for (int m = 0; m < 4; ++m)
                #pragma unroll
                for (int n = 0; n < 4; ++n)
                    acc[m][n] = __builtin_amdgcn_mfma_f32_16x16x32_bf16(af[m], bfr[n], acc[m][n], 0, 0, 0);
        }
        __syncthreads();
    }

    #pragma unroll
    for (int m = 0; m < 4; ++m)
        #pragma unroll
        for (int n = 0; n < 4; ++n)
            #pragma unroll
            for (int j = 0; j < 4; ++j) {
                int row = m0 + wm * 64 + m * 16 + ks * 4 + j;
                int col = n0 + wn * 64 + n * 16 + fr;
                float av = acc[m][n][j];
                if (which == 2) {
                    Cf[(size_t)row * N + col] = av;
                } else {
                    C[(size_t)row * N + col] = (short)f2bf(av);
                    if (which == 0 && col < 1536) {
                        int colh = (col >= 768) ? col - 768 : col;
                        int h = (colh * 683) >> 16;           // colh / 96
                        int d = colh - h * 96;
                        int zq = (col >= 768) ? 8 + h : h;
                        unsigned short vb = f2bf(av + bias[col]);
                        g_QKp[((size_t)zq * MROWS + row) * 128 + d] = (short)vb;
                        if (row >= GR && row < GR + 84) {
                            int zt = (col >= 768) ? h : 8 + h; // k_tab z<8, q_tab z>=8
                            g_TabP[((size_t)zt * 128 + (row - GR)) * 128 + d] = (short)vb;
                        }
                    }
                }
            }
}

// attention mix per (cell, endpoint): one wave per mixed row mr in [0,2044).
// Inline per-head diagonal from g_qkv (+fp32 bias) — R16-proven.
__global__ void k_attn_cell(const float* __restrict__ boundaries,
                            const float* __restrict__ in_proj_b) {
    const int wid = threadIdx.x >> 6, lane = threadIdx.x & 63;
    const int mr = blockIdx.x * 4 + wid;
    if (mr >= 2 * NCELL) return;
    const int cid = mr >> 1, ep = mr & 1;
    const int s = cid / CPS, c = cid - s * CPS;
    const int node = s * NG + c + ep;
    const float tn0 = g_tnode[s * NG + c], tn1 = g_tnode[s * NG + c + 1];
    const float xmid = (s ? -1.f : 1.f) * expm1f(0.5f * (tn0 + tn1));
    int bin, sfi, si;
    const int re = region_of(xmid, boundaries, &bin, &sfi, &si);
    if (ep == 0 && lane == 0) g_creg[cid] = re;
    const int j3[3] = {bin, 20 + sfi, 36 + si * 16 + sfi};

    const int d0 = lane * 12;
    const int h = lane >> 3;
    const float isq = 0.1020620726159658f;

    float sdv = 0.f;
    {
        const unsigned short* qn = (const unsigned short*)g_qkv + (size_t)node * 2304 + d0;
        const unsigned short* kn = qn + 768;
        #pragma unroll
        for (int cc = 0; cc < 12; ++cc)
            sdv += (bf2f(qn[cc]) + in_proj_b[d0 + cc]) * (bf2f(kn[cc]) + in_proj_b[768 + d0 + cc]);
        sdv += __shfl_xor(sdv, 1);
        sdv += __shfl_xor(sdv, 2);
        sdv += __shfl_xor(sdv, 4);
    }

    float sc[4][4];
    sc[0][0] = sdv * isq;
    const size_t su = ((size_t)h * MROWS + node) * 128;
    const size_t sw = ((size_t)(8 + h) * MROWS + node) * 128;
    #pragma unroll
    for (int jj = 0; jj < 3; ++jj) {
        sc[0][jj + 1] = g_scoref[su + j3[jj]] * isq;
        sc[jj + 1][0] = g_scoref[sw + j3[jj]] * isq;
    }
    #pragma unroll
    for (int ii = 0; ii < 3; ++ii)
        #pragma unroll
        for (int jj = 0; jj < 3; ++jj)
            sc[ii + 1][jj + 1] = g_scoref[((size_t)h * MROWS + GR + j3[ii]) * 128 + j3[jj]] * isq;

    const float wt[4] = {0.4f, 0.3f, 0.2f, 0.1f};
    float wtil[4] = {0.f, 0.f, 0.f, 0.f};
    #pragma unroll
    for (int i = 0; i < 4; ++i) {
        float mxs = fmaxf(fmaxf(sc[i][0], sc[i][1]), fmaxf(sc[i][2], sc[i][3]));
        float ex[4], den = 0.f;
        #pragma unroll
        for (int j = 0; j < 4; ++j) { ex[j] = __expf(sc[i][j] - mxs); den += ex[j]; }
        float idn = wt[i] / den;
        #pragma unroll
        for (int j = 0; j < 4; ++j) wtil[j] += ex[j] * idn;
    }

    float bv[12];
    #pragma unroll
    for (int c4 = 0; c4 < 3; ++c4) {
        float4 cc = *reinterpret_cast<const float4*>(&in_proj_b[1536 + d0 + c4 * 4]);
        bv[c4 * 4 + 0] = cc.x; bv[c4 * 4 + 1] = cc.y; bv[c4 * 4 + 2] = cc.z; bv[c4 * 4 + 3] = cc.w;
    }
    float mixv[12];
    {
        const unsigned short* r0 = (const unsigned short*)g_qkv + (size_t)node * 2304 + 1536 + d0;
        #pragma unroll
        for (int cc = 0; cc < 12; ++cc) mixv[cc] = wtil[0] * (bf2f(r0[cc]) + bv[cc]);
    }
    #pragma unroll
    for (int jj = 0; jj < 3; ++jj) {
        const unsigned short* rt = (const unsigned short*)g_qkv + (size_t)(GR + j3[jj]) * 2304 + 1536 + d0;
        const float w = wtil[jj + 1];
        #pragma unroll
        for (int cc = 0; cc < 12; ++cc) mixv[cc] += w * (bf2f(rt[cc]) + bv[cc]);
    }
    unsigned short ob[12];
    #pragma unroll
    for (int cc = 0; cc < 12; ++cc) ob[cc] = f2bf(mixv[cc]);
    unsigned short* mbase = (unsigned short*)g_mixedS + (size_t)mr * DD + d0;
    #pragma unroll
    for (int c4 = 0; c4 < 3; ++c4)
        *reinterpret_cast<ushort4*>(mbase + c4 * 4) =
            make_ushort4(ob[c4 * 4 + 0], ob[c4 * 4 + 1], ob[c4 * 4 + 2], ob[c4 * 4 + 3]);
}

// per element: cell lookup, region check; match -> lerp PRE pair; rare mismatch ->
// exact inline path (inline diag at both nodes — R16-proven).
__global__ void k_final(const float* __restrict__ number, const float* __restrict__ boundaries,
                        const float* __restrict__ in_proj_b, const float* __restrict__ out_proj_b,
                        float* __restrict__ out) {
    const int wid = threadIdx.x >> 6, lane = threadIdx.x & 63;
    const int e = blockIdx.x * 4 + wid;
    const float x = number[e];
    int bin, sfi, si;
    const int re = region_of(x, boundaries, &bin, &sfi, &si);

    const float mx = g_maxabs;
    const float L = log1pf(mx);
    const float dt = L / (float)(NG - 1);
    const float t = log1pf(fabsf(x));
    const int s = (x < 0.f) ? 1 : 0;
    const int base = s * NG;
    int i0 = min(max((int)(t / dt), 0), NG - 2);
    #pragma unroll
    for (int it = 0; it < 2; ++it) {
        if (i0 > 0 && t < g_tnode[base + i0]) --i0;
        else if (i0 < NG - 2 && t >= g_tnode[base + i0 + 1]) ++i0;
    }
    const float tn0 = g_tnode[base + i0], tn1 = g_tnode[base + i0 + 1];
    float w1 = (t - tn0) / (tn1 - tn0);
    w1 = fminf(fmaxf(w1, 0.f), 1.f);
    const float w0 = 1.f - w1;
    const int cid = s * CPS + i0;
    const int d0 = lane * 12;
    float o[12], ss = 0.f;

    if (g_creg[cid] == re) {
        const unsigned short* r0 = (const unsigned short*)g_preS + (size_t)(2 * cid) * DD + d0;
        const unsigned short* r1 = r0 + DD;
        #pragma unroll
        for (int c4 = 0; c4 < 3; ++c4) {
            float4 b = *reinterpret_cast<const float4*>(&out_proj_b[d0 + c4 * 4]);
            ushort4 u0 = *reinterpret_cast<const ushort4*>(r0 + c4 * 4);
            ushort4 u1 = *reinterpret_cast<const ushort4*>(r1 + c4 * 4);
            float p0 = w0 * bf2f(u0.x) + w1 * bf2f(u1.x) + b.x;
            float p1 = w0 * bf2f(u0.y) + w1 * bf2f(u1.y) + b.y;
            float p2 = w0 * bf2f(u0.z) + w1 * bf2f(u1.z) + b.z;
            float p3 = w0 * bf2f(u0.w) + w1 * bf2f(u1.w) + b.w;
            if (p0 != p0) p0 = 0.f;
            if (p1 != p1) p1 = 0.f;
            if (p2 != p2) p2 = 0.f;
            if (p3 != p3) p3 = 0.f;
            o[c4 * 4 + 0] = p0; o[c4 * 4 + 1] = p1; o[c4 * 4 + 2] = p2; o[c4 * 4 + 3] = p3;
            ss += p0 * p0 + p1 * p1 + p2 * p2 + p3 * p3;
        }
    } else {
        const int j3[3] = {bin, 20 + sfi, 36 + si * 16 + sfi};
        const int g0 = base + i0;
        const int h = lane >> 3;
        const float isq = 0.1020620726159658f;
        float s0 = 0.f, s1 = 0.f;
        {
            const unsigned short* q0 = (const unsigned short*)g_qkv + (size_t)g0 * 2304 + d0;
            const unsigned short* k0r = q0 + 768;
            const unsigned short* q1 = q0 + 2304;
            const unsigned short* k1r = q1 + 768;
            #pragma unroll
            for (int cc = 0; cc < 12; ++cc) {
                float bqv = in_proj_b[d0 + cc];
                float bkv = in_proj_b[768 + d0 + cc];
                s0 += (bf2f(q0[cc]) + bqv) * (bf2f(k0r[cc]) + bkv);
                s1 += (bf2f(q1[cc]) + bqv) * (bf2f(k1r[cc]) + bkv);
            }
            s0 += __shfl_xor(s0, 1); s0 += __shfl_xor(s0, 2); s0 += __shfl_xor(s0, 4);
            s1 += __shfl_xor(s1, 1); s1 += __shfl_xor(s1, 2); s1 += __shfl_xor(s1, 4);
        }
        float sc[4][4];
        sc[0][0] = (w0 * s0 + w1 * s1) * isq;
        const size_t su0 = ((size_t)h * MROWS + g0) * 128;
        const size_t sw0 = ((size_t)(8 + h) * MROWS + g0) * 128;
        #pragma unroll
        for (int jj = 0; jj < 3; ++jj) {
            const int j = j3[jj];
            sc[0][jj + 1] = (w0 * g_scoref[su0 + j] + w1 * g_scoref[su0 + 128 + j]) * isq;
            sc[jj + 1][0] = (w0 * g_scoref[sw0 + j] + w1 * g_scoref[sw0 + 128 + j]) * isq;
        }
        #pragma unroll
        for (int ii = 0; ii < 3; ++ii)
            #pragma unroll
            for (int jj = 0; jj < 3; ++jj)
                sc[ii + 1][jj + 1] = g_scoref[((size_t)h * MROWS + GR + j3[ii]) * 128 + j3[jj]] * isq;
        const float wt[4] = {0.4f, 0.3f, 0.2f, 0.1f};
        float wtil[4] = {0.f, 0.f, 0.f, 0.f};
        #pragma unroll
        for (int i = 0; i < 4; ++i) {
            float mxs = fmaxf(fmaxf(sc[i][0], sc[i][1]), fmaxf(sc[i][2], sc[i][3]));
            float ex[4], den = 0.f;
            #pragma unroll
            for (int j = 0; j < 4; ++j) { ex[j] = __expf(sc[i][j] - mxs); den += ex[j]; }
            float idn = wt[i] / den;
            #pragma unroll
            for (int j = 0; j < 4; ++j) wtil[j] += ex[j] * idn;
        }
        float mixv[12];
        {
            const unsigned short* r0 = (const unsigned short*)g_qkv + (size_t)g0 * 2304 + 1536 + d0;
            const unsigned short* r1 = r0 + 2304;
            #pragma unroll
            for (int cc = 0; cc < 12; ++cc) {
                float bvv = in_proj_b[1536 + d0 + cc];
                mixv[cc] = wtil[0] * (w0 * bf2f(r0[cc]) + w1 * bf2f(r1[cc]) + bvv);
            }
        }
        #pragma unroll
        for (int jj = 0; jj < 3; ++jj) {
            const unsigned short* rt = (const unsigned short*)g_qkv + (size_t)(GR + j3[jj]) * 2304 + 1536 + d0;
            const float w = wtil[jj + 1];
            #pragma unroll
            for (int cc = 0; cc < 12; ++cc)
                mixv[cc] += w * (bf2f(rt[cc]) + in_proj_b[1536 + d0 + cc]);
        }
        int mb[12];
        #pragma unroll
        for (int cc = 0; cc < 12; ++cc) mb[cc] = (int)f2bf(mixv[cc]);
        float acc[12];
        #pragma unroll
        for (int cc = 0; cc < 12; ++cc) acc[cc] = 0.f;
        for (int l = 0; l < 64; ++l) {
            float md[12];
            #pragma unroll
            for (int cc = 0; cc < 12; ++cc)
                md[cc] = bf2f((unsigned short)__shfl(mb[cc], l));
            const int dbase = l * 12;
            #pragma unroll
            for (int c2 = 0; c2 < 12; ++c2) {
                const unsigned short* rp = (const unsigned short*)g_WoutBf + (size_t)(d0 + c2) * DD + dbase;
                float a = 0.f;
                #pragma unroll
                for (int cc = 0; cc < 12; ++cc) a += md[cc] * bf2f(rp[cc]);
                acc[c2] += a;
            }
        }
        #pragma unroll
        for (int cc = 0; cc < 12; ++cc) {
            float p = acc[cc] + out_proj_b[d0 + cc];
            if (p != p) p = 0.f;
            o[cc] = p;
            ss += p * p;
        }
    }

    #pragma unroll
    for (int ofs = 32; ofs; ofs >>= 1) ss += __shfl_xor(ss, ofs);
    float inv = 1.f / fmaxf(sqrtf(ss), 1e-12f);
    float* obase = &out[(size_t)e * DD + d0];
    #pragma unroll
    for (int c4 = 0; c4 < 3; ++c4)
        *reinterpret_cast<float4*>(obase + c4 * 4) =
            make_float4(o[c4 * 4 + 0] * inv, o[c4 * 4 + 1] * inv, o[c4 * 4 + 2] * inv, o[c4 * 4 + 3] * inv);
}

extern "C" void kernel_launch(void* const* d_in, const int* in_sizes, int n_in,
                              void* d_out, int out_size, void* d_ws, size_t ws_size,
                              hipStream_t stream) {
    const float* number      = (const float*)d_in[0];
    const float* boundaries  = (const float*)d_in[1];
    const float* mag_emb     = (const float*)d_in[2];
    const float* se_w1       = (const float*)d_in[3];
    const float* se_b1       = (const float*)d_in[4];
    const float* se_g1       = (const float*)d_in[5];
    const float* se_bt1      = (const float*)d_in[6];
    const float* se_w2       = (const float*)d_in[7];
    const float* se_b2       = (const float*)d_in[8];
    const float* ne_w        = (const float*)d_in[9];
    const float* ne_b        = (const float*)d_in[10];
    const float* ne_g        = (const float*)d_in[11];
    const float* ne_bt       = (const float*)d_in[12];
    const float* ce_w        = (const float*)d_in[13];
    const float* ce_b        = (const float*)d_in[14];
    const float* ce_g        = (const float*)d_in[15];
    const float* ce_bt       = (const float*)d_in[16];
    const float* in_proj_w   = (const float*)d_in[17];
    const float* in_proj_b   = (const float*)d_in[18];
    const float* out_proj_w  = (const float*)d_in[19];
    const float* out_proj_b  = (const float*)d_in[20];
    float* out = (float*)d_out;

    k_absmax<<<1, 1024, 0, stream>>>(number);
    k_tables<<<1536, 256, 0, stream>>>(mag_emb, se_w1, se_b1, se_g1, se_bt1, se_w2, se_b2,
                                       ce_w, ce_b, ce_g, ce_bt, in_proj_w, out_proj_w,
                                       ne_w, ne_b, ne_g, ne_bt);
    gemm_bt<<<dim3(2304 / 128, MROWS / 256, 1), 512, 0, stream>>>(0, 2304, DD, in_proj_b);
    gemm_bt<<<dim3(1, MROWS / 256, 16), 512, 0, stream>>>(2, 128, 128, in_proj_b);
    k_attn_cell<<<(2 * NCELL + 3) / 4, 256, 0, stream>>>(boundaries, in_proj_b);
    gemm_bt<<<dim3(DD / 128, MIXR / 256, 1), 512, 0, stream>>>(1, DD, DD, in_proj_b);
    k_final<<<BB / 4, 256, 0, stream>>>(number, boundaries, in_proj_b, out_proj_b, out);
}

// Round 19
// 116.487 us; speedup vs baseline: 1.0983x; 1.0983x over previous
//
#include <hip/hip_runtime.h>
#include <hip/hip_bf16.h>
#include <math.h>

#define BB 16384
#define DD 768
#define NG 512                 // grid nodes per sign
#define GR 1024                // grid node rows (2 signs)
#define MROWS 1280             // 1024 nodes + 84 tables + pad (5*256)
#define CPS 511                // cells per sign
#define NCELL 1022             // total cells
#define MIXR 2048              // mixed rows (2044 used, pad to 8*256)

typedef __attribute__((ext_vector_type(8))) short bf16x8;
typedef __attribute__((ext_vector_type(4))) float f32x4;

// Static device scratch — referenced ONLY from device code.
__device__ short g_Abf[(size_t)MROWS * DD];         // bf16 feats: 0..1023 nodes, 1024..1107 tables, pad 0
__device__ short g_W[(size_t)2304 * DD];            // bf16 in_proj_w
__device__ short g_WoutBf[(size_t)DD * DD];         // bf16 out_proj_w
__device__ short g_qkv[(size_t)MROWS * 2304];       // bf16 q|k|v per row (no bias)
__device__ short g_QKp[(size_t)16 * MROWS * 128];   // z<8: q+bq per head (K-pad 128); z>=8: k+bk
__device__ short g_TabP[(size_t)16 * 128 * 128];    // z<8: k_tab+bk; z>=8: q_tab+bq
__device__ float g_scoref[(size_t)16 * MROWS * 128];// z<8: u-scores; z>=8: w-scores (f32)
__device__ float g_sd[(size_t)MROWS * 8];           // per-head diagonal (q+bq).(k+bk)
__device__ float g_tnode[GR];                       // node t values (snapped)
__device__ int   g_creg[NCELL];                     // packed region per cell (midpoint)
__device__ short g_mixedS[(size_t)MIXR * DD];       // bf16 mixed rows per (cell,endpoint)
__device__ short g_preS[(size_t)MIXR * DD];         // bf16 PRE rows (no out bias)
__device__ float g_maxabs;

__device__ inline unsigned short f2bf(float x) {
    union { float f; unsigned u; } v; v.f = x;
    unsigned r = v.u + 0x7fffu + ((v.u >> 16) & 1u);
    return (unsigned short)(r >> 16);
}
__device__ inline float bf2f(unsigned short h) {
    union { unsigned u; float f; } v; v.u = ((unsigned)h) << 16;
    return v.f;
}

__device__ inline float gelu_exact(float x) {
    return 0.5f * x * (1.0f + erff(x * 0.70710678118654752440f));
}

__device__ inline float block_sum256(float v, float* sbuf) {
    #pragma unroll
    for (int o = 32; o; o >>= 1) v += __shfl_xor(v, o);
    __syncthreads();
    if ((threadIdx.x & 63) == 0) sbuf[threadIdx.x >> 6] = v;
    __syncthreads();
    return sbuf[0] + sbuf[1] + sbuf[2] + sbuf[3];
}

// region of a scalar x (exact reference math)
__device__ inline int region_of(float x, const float* __restrict__ boundaries,
                                int* bin_o, int* sfi_o, int* si_o) {
    int bin = 0;
    #pragma unroll
    for (int j = 0; j < 20; ++j) bin += (boundaries[j] < x) ? 1 : 0;
    bin = min(bin, 19);
    float sf = floorf(log10f(fabsf(x) + 1e-10f));
    int sfi = min(max((int)sf + 10, 0), 15);
    int si = (x > 0.f) ? 2 : ((x < 0.f) ? 0 : 1);
    *bin_o = bin; *sfi_o = sfi; *si_o = si;
    return (bin << 6) | (sfi << 2) | si;
}

// single block, 1024 threads: max|x| -> g_maxabs
__global__ __launch_bounds__(1024) void k_absmax(const float* __restrict__ number) {
    const float4* n4 = reinterpret_cast<const float4*>(number);
    float v = 0.f;
    #pragma unroll
    for (int i = 0; i < 4; ++i) {
        float4 x = n4[threadIdx.x + 1024 * i];
        v = fmaxf(fmaxf(fabsf(x.x), fabsf(x.y)), fmaxf(fmaxf(fabsf(x.z), fabsf(x.w)), v));
    }
    #pragma unroll
    for (int o = 32; o; o >>= 1) v = fmaxf(v, __shfl_xor(v, o));
    __shared__ float sb[16];
    if ((threadIdx.x & 63) == 0) sb[threadIdx.x >> 6] = v;
    __syncthreads();
    if (threadIdx.x == 0) {
        float m = sb[0];
        #pragma unroll
        for (int i = 1; i < 16; ++i) m = fmaxf(m, sb[i]);
        g_maxabs = m;
    }
}

// Block roles REORDERED so the long-pole fgrid blocks launch FIRST:
// 0-255 fgrid node rows (breakpoint snapping, writes g_tnode),
// 256-831 weight cast (4 float4/thread), 832-851 mag rows, 852-867 scale rows,
// 868-915 ctx rows, 916-1087 Abf pad zero.
__global__ void k_tables(const float* __restrict__ mag_emb,
                         const float* __restrict__ se_w1, const float* __restrict__ se_b1,
                         const float* __restrict__ se_g1, const float* __restrict__ se_bt1,
                         const float* __restrict__ se_w2, const float* __restrict__ se_b2,
                         const float* __restrict__ ce_w, const float* __restrict__ ce_b,
                         const float* __restrict__ ce_g, const float* __restrict__ ce_bt,
                         const float* __restrict__ in_proj_w, const float* __restrict__ out_proj_w,
                         const float* __restrict__ ne_w, const float* __restrict__ ne_b,
                         const float* __restrict__ ne_g, const float* __restrict__ ne_bt) {
    __shared__ float sbuf[4];
    __shared__ float sh[192];
    const int t = threadIdx.x;
    const int blk = blockIdx.x;
    if (blk < 256) {
        // fgrid node rows: one wave per node r in [0,1024). Snap interior nodes
        // to region breakpoints (decades 10^k, k=0..15; boundary magnitudes
        // 10^(1.875j), j=0..8) so cells are region-uniform.
        const int wid = t >> 6, lane = t & 63;
        const int r = blk * 4 + wid;
        const float mx = g_maxabs;
        const float L = log1pf(mx);
        const float dt = L / (float)(NG - 1);
        const int ri = r & (NG - 1);
        float tt = (float)ri * dt;
        if (ri > 0 && ri < NG - 1) {
            #pragma unroll
            for (int k = 0; k < 16; ++k) {
                float tb = log1pf(__expf((float)k * 2.302585093f));
                if (tb < L && (int)(tb / dt + 0.5f) == ri) tt = tb;
            }
            #pragma unroll
            for (int j = 0; j < 9; ++j) {
                float tb = log1pf(__expf((float)j * 1.875f * 2.302585093f));
                if (tb < L && (int)(tb / dt + 0.5f) == ri) tt = tb;
            }
        }
        if (lane == 0) g_tnode[r] = tt;
        const float ax = expm1f(tt);
        const float sgn = (r >= NG) ? -1.f : 1.f;
        const float a = sgn * ax / (mx + 1e-10f);
        const float b = tt / (L + 1e-10f);
        float pre[12];
        float s = 0.f;
        #pragma unroll
        for (int j = 0; j < 12; ++j) {
            int d = lane + 64 * j;
            float2 w = *reinterpret_cast<const float2*>(&ne_w[2 * d]);
            pre[j] = a * w.x + b * w.y + ne_b[d];
            s += pre[j];
        }
        #pragma unroll
        for (int o = 32; o; o >>= 1) s += __shfl_xor(s, o);
        float m = s / 768.f;
        float q = 0.f;
        #pragma unroll
        for (int j = 0; j < 12; ++j) { float dd = pre[j] - m; q += dd * dd; }
        #pragma unroll
        for (int o = 32; o; o >>= 1) q += __shfl_xor(q, o);
        float inv = 1.f / sqrtf(q / 768.f + 1e-5f);
        #pragma unroll
        for (int j = 0; j < 12; ++j) {
            int d = lane + 64 * j;
            g_Abf[(size_t)r * DD + d] = (short)f2bf(gelu_exact((pre[j] - m) * inv * ne_g[d] + ne_bt[d]));
        }
    } else if (blk < 832) {
        // weight cast: 4 float4 per thread, 1024 float4 per block (576 blocks).
        #pragma unroll
        for (int ii = 0; ii < 4; ++ii) {
            int i = (blk - 256) * 1024 + t + 256 * ii;
            const bool second = (i >= 442368);
            const float* src = second ? out_proj_w : in_proj_w;
            short* dst = second ? g_WoutBf : g_W;
            int j = second ? (i - 442368) : i;
            const float4 v = *reinterpret_cast<const float4*>(&src[(size_t)j * 4]);
            ushort4 o;
            o.x = f2bf(v.x); o.y = f2bf(v.y); o.z = f2bf(v.z); o.w = f2bf(v.w);
            *reinterpret_cast<ushort4*>(&dst[(size_t)j * 4]) = o;
        }
    } else if (blk < 852) {
        int mrow = blk - 832;
        #pragma unroll
        for (int i = 0; i < 3; ++i) {
            int d = t + 256 * i;
            g_Abf[(size_t)(GR + mrow) * DD + d] = (short)f2bf(mag_emb[mrow * DD + d]);
        }
    } else if (blk < 868) {
        int sfi = blk - 852;
        float sf = (float)(sfi - 10);
        float pre = 0.f;
        if (t < 192) pre = sf * se_w1[t] + se_b1[t];
        float s = block_sum256(t < 192 ? pre : 0.f, sbuf);
        float m = s / 192.f;
        float dd = (t < 192) ? (pre - m) : 0.f;
        float vv = block_sum256(dd * dd, sbuf);
        float inv = 1.f / sqrtf(vv / 192.f + 1e-5f);
        if (t < 192) sh[t] = gelu_exact((pre - m) * inv * se_g1[t] + se_bt1[t]);
        __syncthreads();
        #pragma unroll
        for (int i = 0; i < 3; ++i) {
            int d = t + 256 * i;
            float acc = se_b2[d];
            for (int j = 0; j < 192; ++j) acc += se_w2[d * 192 + j] * sh[j];
            g_Abf[(size_t)(GR + 20 + sfi) * DD + d] = (short)f2bf(acc);
        }
    } else if (blk < 916) {
        int c = blk - 868;
        int si = c >> 4, sfi = c & 15;
        float f0 = (float)(si - 1);
        float f1 = (float)(sfi - 10) / 16.f;
        float pre[3];
        float ps = 0.f;
        #pragma unroll
        for (int i = 0; i < 3; ++i) {
            int d = t + 256 * i;
            pre[i] = f0 * ce_w[2 * d] + f1 * ce_w[2 * d + 1] + ce_b[d];
            ps += pre[i];
        }
        float s = block_sum256(ps, sbuf);
        float m = s / 768.f;
        float qs = 0.f;
        #pragma unroll
        for (int i = 0; i < 3; ++i) { float dd = pre[i] - m; qs += dd * dd; }
        float vv = block_sum256(qs, sbuf);
        float inv = 1.f / sqrtf(vv / 768.f + 1e-5f);
        #pragma unroll
        for (int i = 0; i < 3; ++i) {
            int d = t + 256 * i;
            g_Abf[(size_t)(GR + 36 + c) * DD + d] =
                (short)f2bf(gelu_exact((pre[i] - m) * inv * ce_g[d] + ce_bt[d]));
        }
    } else {
        int row = GR + 84 + (blk - 916);   // 1108 .. 1279
        #pragma unroll
        for (int i = 0; i < 3; ++i) g_Abf[(size_t)row * DD + t + 256 * i] = 0;
    }
}

// C[m][n] = sum_k A[m][k]*B[n][k] (bf16 in, fp32 MFMA accum). R10 config.
// which==0: g_Abf(1280) @ g_W -> g_qkv (N=2304)
// which==1: g_mixedS(2048) @ g_WoutBf -> g_preS (N=768)
// which==2: per-head score GEMMs, grid.z=16: g_QKp[z] @ g_TabP[z] -> g_scoref[z] F32
__global__ __launch_bounds__(512, 4) void gemm_bt(int which, int N, int K) {
    const int z = blockIdx.z;
    const short* A = (which == 0) ? g_Abf : (which == 1) ? g_mixedS : g_QKp + (size_t)z * MROWS * 128;
    const short* B = (which == 0) ? g_W : (which == 2) ? g_TabP + (size_t)z * 128 * 128 : g_WoutBf;
    short* C = (which == 0) ? g_qkv : g_preS;
    float* Cf = g_scoref + (size_t)z * MROWS * 128;

    __shared__ short As[256 * 64];
    __shared__ short Bs[128 * 64];
    const int t = threadIdx.x;

    const int GX = gridDim.x;
    const int nwg = GX * gridDim.y;
    const int lin = blockIdx.y * GX + blockIdx.x;
    const int qq = nwg >> 3, rr = nwg & 7;
    const int xcd = lin & 7, idx = lin >> 3;
    const int nl = (xcd < rr ? xcd * (qq + 1) : rr * (qq + 1) + (xcd - rr) * qq) + idx;
    const int m0 = (nl / GX) * 256, n0 = (nl % GX) * 128;

    const int wid = t >> 6, lane = t & 63;
    const int wm = wid >> 1, wn = wid & 1;
    const int fr = lane & 15, ks = lane >> 4;

    f32x4 acc[4][4];
    #pragma unroll
    for (int m = 0; m < 4; ++m)
        #pragma unroll
        for (int n = 0; n < 4; ++n) acc[m][n] = (f32x4){0.f, 0.f, 0.f, 0.f};

    for (int k0 = 0; k0 < K; k0 += 64) {
        #pragma unroll
        for (int i = 0; i < 4; ++i) {
            int L = t + 512 * i;
            int row = L >> 3, sp = L & 7;
            int s = sp ^ (row & 7);
            const short* srcA = A + (size_t)(m0 + row) * K + k0 + s * 8;
            __builtin_amdgcn_global_load_lds(
                (const __attribute__((address_space(1))) unsigned int*)srcA,
                (__attribute__((address_space(3))) unsigned int*)((char*)As + L * 16), 16, 0, 0);
        }
        #pragma unroll
        for (int i = 0; i < 2; ++i) {
            int L = t + 512 * i;
            int row = L >> 3, sp = L & 7;
            int s = sp ^ (row & 7);
            const short* srcB = B + (size_t)(n0 + row) * K + k0 + s * 8;
            __builtin_amdgcn_global_load_lds(
                (const __attribute__((address_space(1))) unsigned int*)srcB,
                (__attribute__((address_space(3))) unsigned int*)((char*)Bs + L * 16), 16, 0, 0);
        }
        __syncthreads();
        #pragma unroll
        for (int kk = 0; kk < 2; ++kk) {
            bf16x8 af[4], bfr[4];
            #pragma unroll
            for (int m = 0; m < 4; ++m) {
                int row = wm * 64 + m * 16 + fr;
                int off = row * 128 + ((((kk << 2) | ks) ^ (row & 7)) * 16);
                af[m] = *(const bf16x8*)((const char*)As + off);
            }
            #pragma unroll
            for (int n = 0; n < 4; ++n) {
                int row = wn * 64 + n * 16 + fr;
                int off = row * 128 + ((((kk << 2) | ks) ^ (row & 7)) * 16);
                bfr[n] = *(const bf16x8*)((const char*)Bs + off);
            }
            #pragma unroll
            for (int m = 0; m < 4; ++m)
                #pragma unroll
                for (int n = 0; n < 4; ++n)
                    acc[m][n] = __builtin_amdgcn_mfma_f32_16x16x32_bf16(af[m], bfr[n], acc[m][n], 0, 0, 0);
        }
        __syncthreads();
    }

    #pragma unroll
    for (int m = 0; m < 4; ++m)
        #pragma unroll
        for (int n = 0; n < 4; ++n)
            #pragma unroll
            for (int j = 0; j < 4; ++j) {
                int row = m0 + wm * 64 + m * 16 + ks * 4 + j;
                int col = n0 + wn * 64 + n * 16 + fr;
                if (which == 2) Cf[(size_t)row * N + col] = acc[m][n][j];
                else C[(size_t)row * N + col] = (short)f2bf(acc[m][n][j]);
            }
}

// repack q/k (+bias) per head (K pad 96->128) + per-head diagonal. (R15 verbatim)
__global__ void k_repack(const float* __restrict__ in_proj_b) {
    const int blk = blockIdx.x;
    if (blk < 1280) {
        const int idx = blk * 256 + threadIdx.x;
        const int z = idx / (MROWS * 16);
        const int rem = idx % (MROWS * 16);
        const int g = rem >> 4, c8 = rem & 15, d = c8 * 8;
        unsigned short o[8] = {0, 0, 0, 0, 0, 0, 0, 0};
        if (d < 96) {
            const int h = z & 7;
            const int off = (z < 8) ? 0 : 768;
            const float* bias = in_proj_b + off + h * 96 + d;
            const unsigned short* src = (const unsigned short*)g_qkv + (size_t)g * 2304 + off + h * 96 + d;
            #pragma unroll
            for (int c = 0; c < 8; ++c) o[c] = f2bf(bf2f(src[c]) + bias[c]);
        }
        *reinterpret_cast<bf16x8*>(g_QKp + (size_t)idx * 8) = *(const bf16x8*)o;
    } else if (blk < 1408) {
        const int i2 = (blk - 1280) * 256 + threadIdx.x;
        const int z = i2 / (128 * 16);
        const int rem = i2 % (128 * 16);
        const int j = rem >> 4, c8 = rem & 15, d = c8 * 8;
        unsigned short o[8] = {0, 0, 0, 0, 0, 0, 0, 0};
        if (d < 96 && j < 84) {
            const int h = z & 7;
            const int off = (z < 8) ? 768 : 0;
            const float* bias = in_proj_b + off + h * 96 + d;
            const unsigned short* src = (const unsigned short*)g_qkv + (size_t)(GR + j) * 2304 + off + h * 96 + d;
            #pragma unroll
            for (int c = 0; c < 8; ++c) o[c] = f2bf(bf2f(src[c]) + bias[c]);
        }
        *reinterpret_cast<bf16x8*>(g_TabP + (size_t)i2 * 8) = *(const bf16x8*)o;
    } else {
        const int wid = threadIdx.x >> 6, lane = threadIdx.x & 63;
        const int g = (blk - 1408) * 4 + wid;
        if (g >= GR + 84) return;
        const int h = lane >> 3, sub = lane & 7;
        const int d0 = h * 96 + sub * 12;
        const unsigned short* qrow = (const unsigned short*)g_qkv + (size_t)g * 2304 + d0;
        const unsigned short* krow = qrow + 768;
        const float* bq = in_proj_b + d0;
        const float* bk = in_proj_b + 768 + d0;
        float s = 0.f;
        #pragma unroll
        for (int c = 0; c < 12; ++c)
            s += (bf2f(qrow[c]) + bq[c]) * (bf2f(krow[c]) + bk[c]);
        s += __shfl_xor(s, 1);
        s += __shfl_xor(s, 2);
        s += __shfl_xor(s, 4);
        if (sub == 0) g_sd[(size_t)g * 8 + h] = s;
    }
}

// attention mix per (cell, endpoint): one wave per mixed row mr in [0,2044).
// Uses the CELL's region (midpoint) at BOTH endpoint nodes.
__global__ void k_attn_cell(const float* __restrict__ boundaries,
                            const float* __restrict__ in_proj_b) {
    const int wid = threadIdx.x >> 6, lane = threadIdx.x & 63;
    const int mr = blockIdx.x * 4 + wid;
    if (mr >= 2 * NCELL) return;
    const int cid = mr >> 1, ep = mr & 1;
    const int s = cid / CPS, c = cid - s * CPS;
    const int node = s * NG + c + ep;
    const float tn0 = g_tnode[s * NG + c], tn1 = g_tnode[s * NG + c + 1];
    const float xmid = (s ? -1.f : 1.f) * expm1f(0.5f * (tn0 + tn1));
    int bin, sfi, si;
    const int re = region_of(xmid, boundaries, &bin, &sfi, &si);
    if (ep == 0 && lane == 0) g_creg[cid] = re;
    const int j3[3] = {bin, 20 + sfi, 36 + si * 16 + sfi};

    const int h = lane >> 3;
    const float isq = 0.1020620726159658f;
    float sc[4][4];
    sc[0][0] = g_sd[(size_t)node * 8 + h] * isq;
    const size_t su = ((size_t)h * MROWS + node) * 128;
    const size_t sw = ((size_t)(8 + h) * MROWS + node) * 128;
    #pragma unroll
    for (int jj = 0; jj < 3; ++jj) {
        sc[0][jj + 1] = g_scoref[su + j3[jj]] * isq;
        sc[jj + 1][0] = g_scoref[sw + j3[jj]] * isq;
    }
    #pragma unroll
    for (int ii = 0; ii < 3; ++ii)
        #pragma unroll
        for (int jj = 0; jj < 3; ++jj)
            sc[ii + 1][jj + 1] = g_scoref[((size_t)h * MROWS + GR + j3[ii]) * 128 + j3[jj]] * isq;

    const float wt[4] = {0.4f, 0.3f, 0.2f, 0.1f};
    float wtil[4] = {0.f, 0.f, 0.f, 0.f};
    #pragma unroll
    for (int i = 0; i < 4; ++i) {
        float mxs = fmaxf(fmaxf(sc[i][0], sc[i][1]), fmaxf(sc[i][2], sc[i][3]));
        float ex[4], den = 0.f;
        #pragma unroll
        for (int j = 0; j < 4; ++j) { ex[j] = __expf(sc[i][j] - mxs); den += ex[j]; }
        float idn = wt[i] / den;
        #pragma unroll
        for (int j = 0; j < 4; ++j) wtil[j] += ex[j] * idn;
    }

    const int d0 = lane * 12;
    float bv[12];
    #pragma unroll
    for (int c4 = 0; c4 < 3; ++c4) {
        float4 cc = *reinterpret_cast<const float4*>(&in_proj_b[1536 + d0 + c4 * 4]);
        bv[c4 * 4 + 0] = cc.x; bv[c4 * 4 + 1] = cc.y; bv[c4 * 4 + 2] = cc.z; bv[c4 * 4 + 3] = cc.w;
    }
    float mixv[12];
    {
        const unsigned short* r0 = (const unsigned short*)g_qkv + (size_t)node * 2304 + 1536 + d0;
        #pragma unroll
        for (int cc = 0; cc < 12; ++cc) mixv[cc] = wtil[0] * (bf2f(r0[cc]) + bv[cc]);
    }
    #pragma unroll
    for (int jj = 0; jj < 3; ++jj) {
        const unsigned short* rt = (const unsigned short*)g_qkv + (size_t)(GR + j3[jj]) * 2304 + 1536 + d0;
        const float w = wtil[jj + 1];
        #pragma unroll
        for (int cc = 0; cc < 12; ++cc) mixv[cc] += w * (bf2f(rt[cc]) + bv[cc]);
    }
    unsigned short ob[12];
    #pragma unroll
    for (int cc = 0; cc < 12; ++cc) ob[cc] = f2bf(mixv[cc]);
    unsigned short* mbase = (unsigned short*)g_mixedS + (size_t)mr * DD + d0;
    #pragma unroll
    for (int c4 = 0; c4 < 3; ++c4)
        *reinterpret_cast<ushort4*>(mbase + c4 * 4) =
            make_ushort4(ob[c4 * 4 + 0], ob[c4 * 4 + 1], ob[c4 * 4 + 2], ob[c4 * 4 + 3]);
}

// per element: cell lookup, region check; match -> lerp PRE pair; rare mismatch ->
// exact inline path (score lerp + wave matvec over L2-hot Wout).
__global__ void k_final(const float* __restrict__ number, const float* __restrict__ boundaries,
                        const float* __restrict__ in_proj_b, const float* __restrict__ out_proj_b,
                        float* __restrict__ out) {
    const int wid = threadIdx.x >> 6, lane = threadIdx.x & 63;
    const int e = blockIdx.x * 4 + wid;
    const float x = number[e];
    int bin, sfi, si;
    const int re = region_of(x, boundaries, &bin, &sfi, &si);

    const float mx = g_maxabs;
    const float L = log1pf(mx);
    const float dt = L / (float)(NG - 1);
    const float t = log1pf(fabsf(x));
    const int s = (x < 0.f) ? 1 : 0;
    const int base = s * NG;
    int i0 = min(max((int)(t / dt), 0), NG - 2);
    #pragma unroll
    for (int it = 0; it < 2; ++it) {
        if (i0 > 0 && t < g_tnode[base + i0]) --i0;
        else if (i0 < NG - 2 && t >= g_tnode[base + i0 + 1]) ++i0;
    }
    const float tn0 = g_tnode[base + i0], tn1 = g_tnode[base + i0 + 1];
    float w1 = (t - tn0) / (tn1 - tn0);
    w1 = fminf(fmaxf(w1, 0.f), 1.f);
    const float w0 = 1.f - w1;
    const int cid = s * CPS + i0;
    const int d0 = lane * 12;
    float o[12], ss = 0.f;

    if (g_creg[cid] == re) {
        const unsigned short* r0 = (const unsigned short*)g_preS + (size_t)(2 * cid) * DD + d0;
        const unsigned short* r1 = r0 + DD;
        #pragma unroll
        for (int c4 = 0; c4 < 3; ++c4) {
            float4 b = *reinterpret_cast<const float4*>(&out_proj_b[d0 + c4 * 4]);
            ushort4 u0 = *reinterpret_cast<const ushort4*>(r0 + c4 * 4);
            ushort4 u1 = *reinterpret_cast<const ushort4*>(r1 + c4 * 4);
            float p0 = w0 * bf2f(u0.x) + w1 * bf2f(u1.x) + b.x;
            float p1 = w0 * bf2f(u0.y) + w1 * bf2f(u1.y) + b.y;
            float p2 = w0 * bf2f(u0.z) + w1 * bf2f(u1.z) + b.z;
            float p3 = w0 * bf2f(u0.w) + w1 * bf2f(u1.w) + b.w;
            if (p0 != p0) p0 = 0.f;
            if (p1 != p1) p1 = 0.f;
            if (p2 != p2) p2 = 0.f;
            if (p3 != p3) p3 = 0.f;
            o[c4 * 4 + 0] = p0; o[c4 * 4 + 1] = p1; o[c4 * 4 + 2] = p2; o[c4 * 4 + 3] = p3;
            ss += p0 * p0 + p1 * p1 + p2 * p2 + p3 * p3;
        }
    } else {
        const int j3[3] = {bin, 20 + sfi, 36 + si * 16 + sfi};
        const int g0 = base + i0;
        const int h = lane >> 3;
        const float isq = 0.1020620726159658f;
        float sc[4][4];
        sc[0][0] = (w0 * g_sd[(size_t)g0 * 8 + h] + w1 * g_sd[(size_t)(g0 + 1) * 8 + h]) * isq;
        const size_t su0 = ((size_t)h * MROWS + g0) * 128;
        const size_t sw0 = ((size_t)(8 + h) * MROWS + g0) * 128;
        #pragma unroll
        for (int jj = 0; jj < 3; ++jj) {
            const int j = j3[jj];
            sc[0][jj + 1] = (w0 * g_scoref[su0 + j] + w1 * g_scoref[su0 + 128 + j]) * isq;
            sc[jj + 1][0] = (w0 * g_scoref[sw0 + j] + w1 * g_scoref[sw0 + 128 + j]) * isq;
        }
        #pragma unroll
        for (int ii = 0; ii < 3; ++ii)
            #pragma unroll
            for (int jj = 0; jj < 3; ++jj)
                sc[ii + 1][jj + 1] = g_scoref[((size_t)h * MROWS + GR + j3[ii]) * 128 + j3[jj]] * isq;
        const float wt[4] = {0.4f, 0.3f, 0.2f, 0.1f};
        float wtil[4] = {0.f, 0.f, 0.f, 0.f};
        #pragma unroll
        for (int i = 0; i < 4; ++i) {
            float mxs = fmaxf(fmaxf(sc[i][0], sc[i][1]), fmaxf(sc[i][2], sc[i][3]));
            float ex[4], den = 0.f;
            #pragma unroll
            for (int j = 0; j < 4; ++j) { ex[j] = __expf(sc[i][j] - mxs); den += ex[j]; }
            float idn = wt[i] / den;
            #pragma unroll
            for (int j = 0; j < 4; ++j) wtil[j] += ex[j] * idn;
        }
        float mixv[12];
        {
            const unsigned short* r0 = (const unsigned short*)g_qkv + (size_t)g0 * 2304 + 1536 + d0;
            const unsigned short* r1 = r0 + 2304;
            #pragma unroll
            for (int cc = 0; cc < 12; ++cc) {
                float bvv = in_proj_b[1536 + d0 + cc];
                mixv[cc] = wtil[0] * (w0 * bf2f(r0[cc]) + w1 * bf2f(r1[cc]) + bvv);
            }
        }
        #pragma unroll
        for (int jj = 0; jj < 3; ++jj) {
            const unsigned short* rt = (const unsigned short*)g_qkv + (size_t)(GR + j3[jj]) * 2304 + 1536 + d0;
            const float w = wtil[jj + 1];
            #pragma unroll
            for (int cc = 0; cc < 12; ++cc)
                mixv[cc] += w * (bf2f(rt[cc]) + in_proj_b[1536 + d0 + cc]);
        }
        int mb[12];
        #pragma unroll
        for (int cc = 0; cc < 12; ++cc) mb[cc] = (int)f2bf(mixv[cc]);
        float acc[12];
        #pragma unroll
        for (int cc = 0; cc < 12; ++cc) acc[cc] = 0.f;
        for (int l = 0; l < 64; ++l) {
            float md[12];
            #pragma unroll
            for (int cc = 0; cc < 12; ++cc)
                md[cc] = bf2f((unsigned short)__shfl(mb[cc], l));
            const int dbase = l * 12;
            #pragma unroll
            for (int c2 = 0; c2 < 12; ++c2) {
                const unsigned short* rp = (const unsigned short*)g_WoutBf + (size_t)(d0 + c2) * DD + dbase;
                float a = 0.f;
                #pragma unroll
                for (int cc = 0; cc < 12; ++cc) a += md[cc] * bf2f(rp[cc]);
                acc[c2] += a;
            }
        }
        #pragma unroll
        for (int cc = 0; cc < 12; ++cc) {
            float p = acc[cc] + out_proj_b[d0 + cc];
            if (p != p) p = 0.f;
            o[cc] = p;
            ss += p * p;
        }
    }

    #pragma unroll
    for (int ofs = 32; ofs; ofs >>= 1) ss += __shfl_xor(ss, ofs);
    float inv = 1.f / fmaxf(sqrtf(ss), 1e-12f);
    float* obase = &out[(size_t)e * DD + d0];
    #pragma unroll
    for (int c4 = 0; c4 < 3; ++c4)
        *reinterpret_cast<float4*>(obase + c4 * 4) =
            make_float4(o[c4 * 4 + 0] * inv, o[c4 * 4 + 1] * inv, o[c4 * 4 + 2] * inv, o[c4 * 4 + 3] * inv);
}

extern "C" void kernel_launch(void* const* d_in, const int* in_sizes, int n_in,
                              void* d_out, int out_size, void* d_ws, size_t ws_size,
                              hipStream_t stream) {
    const float* number      = (const float*)d_in[0];
    const float* boundaries  = (const float*)d_in[1];
    const float* mag_emb     = (const float*)d_in[2];
    const float* se_w1       = (const float*)d_in[3];
    const float* se_b1       = (const float*)d_in[4];
    const float* se_g1       = (const float*)d_in[5];
    const float* se_bt1      = (const float*)d_in[6];
    const float* se_w2       = (const float*)d_in[7];
    const float* se_b2       = (const float*)d_in[8];
    const float* ne_w        = (const float*)d_in[9];
    const float* ne_b        = (const float*)d_in[10];
    const float* ne_g        = (const float*)d_in[11];
    const float* ne_bt       = (const float*)d_in[12];
    const float* ce_w        = (const float*)d_in[13];
    const float* ce_b        = (const float*)d_in[14];
    const float* ce_g        = (const float*)d_in[15];
    const float* ce_bt       = (const float*)d_in[16];
    const float* in_proj_w   = (const float*)d_in[17];
    const float* in_proj_b   = (const float*)d_in[18];
    const float* out_proj_w  = (const float*)d_in[19];
    const float* out_proj_b  = (const float*)d_in[20];
    float* out = (float*)d_out;

    k_absmax<<<1, 1024, 0, stream>>>(number);
    k_tables<<<1088, 256, 0, stream>>>(mag_emb, se_w1, se_b1, se_g1, se_bt1, se_w2, se_b2,
                                       ce_w, ce_b, ce_g, ce_bt, in_proj_w, out_proj_w,
                                       ne_w, ne_b, ne_g, ne_bt);
    gemm_bt<<<dim3(2304 / 128, MROWS / 256, 1), 512, 0, stream>>>(0, 2304, DD);
    k_repack<<<1685, 256, 0, stream>>>(in_proj_b);
    gemm_bt<<<dim3(1, MROWS / 256, 16), 512, 0, stream>>>(2, 128, 128);
    k_attn_cell<<<(2 * NCELL + 3) / 4, 256, 0, stream>>>(boundaries, in_proj_b);
    gemm_bt<<<dim3(DD / 128, MIXR / 256, 1), 512, 0, stream>>>(1, DD, DD);
    k_final<<<BB / 4, 256, 0, stream>>>(number, boundaries, in_proj_b, out_proj_b, out);
}